// Round 23
// baseline (153.301 us; speedup 1.0000x reference)
//
#include <hip/hip_runtime.h>
#include <hip/hip_bf16.h>

#define B_ 2
#define N_ 512
#define E_ 64
#define G_ 192
#define LIN_IN_ 192

typedef __attribute__((ext_vector_type(8))) short bf16x8;
typedef __attribute__((ext_vector_type(4))) float f32x4;

__device__ __forceinline__ unsigned short f2bf(float x) {
  unsigned u = __float_as_uint(x);
  unsigned r = (u + 0x7FFFu + ((u >> 16) & 1u)) >> 16;
  return (unsigned short)r;
}
// fast sigmoid: v_rcp_f32 (1 ULP) instead of IEEE divide (R12-verified correct)
__device__ __forceinline__ float sigm(float x) {
  return __builtin_amdgcn_rcpf(1.f + __expf(-x));
}
__device__ __forceinline__ float tanh_f(float x) {
  float e = __expf(-2.f * fabsf(x));
  return copysignf((1.f - e) * __builtin_amdgcn_rcpf(1.f + e), x);
}
__device__ __forceinline__ bf16x8 pack8(const float* t) {
  union { bf16x8 v; __hip_bfloat16 h[8]; } u;
#pragma unroll
  for (int k = 0; k < 8; ++k) u.h[k] = __float2bfloat16(t[k]);
  return u.v;
}

// ---------- prep1: Bt[384][64] bf16 = [W2e (wih·We) ; whh]; V1 = wih·W1,
//            V2 = wih·W2h (fp32); ub = wih·b_lin ----------
__global__ __launch_bounds__(64) void prep1(const float* __restrict__ Wlin,
                                            const float* __restrict__ blin,
                                            const float* __restrict__ wih,
                                            const float* __restrict__ whh,
                                            unsigned short* __restrict__ Bt,
                                            float* __restrict__ V1,
                                            float* __restrict__ V2,
                                            float* __restrict__ ub) {
  int g = blockIdx.x;   // 0..383
  int f = threadIdx.x;  // 0..63
  if (g < G_) {
    const float* wr = wih + g * 64;  // uniform -> s_load
    float aw = 0.f, a1 = 0.f, a2 = 0.f;
#pragma unroll
    for (int e = 0; e < 64; ++e) {
      float wv = wr[e];
      a1 += wv * Wlin[e * LIN_IN_ + f];          // V1 = wih·W1
      aw += wv * Wlin[e * LIN_IN_ + 64 + f];     // W2e = wih·We
      a2 += wv * Wlin[e * LIN_IN_ + 128 + f];    // V2 = wih·W2h
    }
    Bt[g * 64 + f] = f2bf(aw);
    V1[g * 64 + f] = a1;
    V2[g * 64 + f] = a2;
    if (f == 0) {
      float s = 0.f;
      for (int e = 0; e < 64; ++e) s += wr[e] * blin[e];
      ub[g] = s;
    }
  } else {
    int gh = g - G_;
    Bt[g * 64 + f] = f2bf(whh[gh * 64 + f]);
  }
}

// ---------- prep2: u1[row,g] = V1[g,:]·h[row,:]; u2p[row,g] = V2[g,:]·h[row,:] + ub[g] ----------
__global__ __launch_bounds__(192) void prep2(const float* __restrict__ h,
                                             const float* __restrict__ V1,
                                             const float* __restrict__ V2,
                                             const float* __restrict__ ub,
                                             float* __restrict__ u1,
                                             float* __restrict__ u2p) {
  int row = blockIdx.x;   // b*N+n
  int g = threadIdx.x;    // 0..191
  const float* hr = h + (size_t)row * 64;  // uniform
  float a1 = 0.f, a2 = 0.f;
#pragma unroll
  for (int f = 0; f < 64; ++f) {
    float hv = hr[f];
    a1 += V1[g * 64 + f] * hv;
    a2 += V2[g * 64 + f] * hv;
  }
  u1[(size_t)row * G_ + g] = a1;
  u2p[(size_t)row * G_ + g] = a2 + ub[g];
}

// ---------- fusedT19: R22 champion fusedT14 (124.2us) + double-buffered s=0
// weight fragments: mg+1's 6 ds_read_b128 (wf0) issued BEFORE mg's epilogue,
// hiding their issue+latency head (~150-250cy, previously fully exposed at
// each of 8 mg boundaries per wave since the LGKM queue drains during the
// long TRANS gate chain). +24 VGPR (~152) — free zone: LDS caps occupancy
// at 12 waves/CU for VGPR <= 170. ----------
__global__ __launch_bounds__(256) void fusedT19(const float* __restrict__ edge,
                                                const float* __restrict__ adj,
                                                const unsigned short* __restrict__ BtW,
                                                const float* __restrict__ u1,
                                                const float* __restrict__ u2p,
                                                const float* __restrict__ bih,
                                                const float* __restrict__ bhh,
                                                float* __restrict__ out) {
  __shared__ uint4 Bs4[3072];  // 48 KB: 384 rows x 128B, XOR-swizzled (0-conflict verified)
  char* Bc = (char*)Bs4;
  int tid = threadIdx.x;

  int lane = tid & 63, wave = tid >> 6;
  unsigned pbase = blockIdx.x * 256u + wave * 32u;
  int b = pbase >> 18;
  int iN = (pbase >> 9) & 511;
  int lr = lane & 15, lg = lane >> 4;

  // ---- issue tile-0 edge/adj loads FIRST: latency overlaps staging+barrier ----
  float4 raw[2][4];
  float adjraw[2];
#pragma unroll
  for (int np = 0; np < 2; ++np) {
    const float* er = edge + (size_t)(pbase + np * 16 + lr) * 64 + lg * 8;
    raw[np][0] = *(const float4*)er;
    raw[np][1] = *(const float4*)(er + 4);
    raw[np][2] = *(const float4*)(er + 32);
    raw[np][3] = *(const float4*)(er + 36);
    adjraw[np] = adj[pbase + np * 16 + lr];
  }

  // ---- weight staging (overlapped with the edge loads above) ----
  const uint4* src = (const uint4*)BtW;
#pragma unroll
  for (int it = 0; it < 12; ++it) {
    int c = tid + it * 256;          // 3072 chunks of 16B
    int row = c >> 3;
    *(uint4*)(Bc + row * 128 + (((c & 7) * 16) ^ ((row & 7) << 4))) = src[c];
  }
  __syncthreads();

  // bpermute source-lane addresses (byte addr = srclane*4)
  int addrE = (lr + 16 * (lg >> 1)) << 2;   // mg even
  int addrO = addrE + 128;                  // mg odd

  // u2 row is shared by both tiles (same b, iN) — hoisted
  const float* u2r = u2p + ((size_t)(b * N_ + iN)) * G_;

#pragma unroll
  for (int t = 0; t < 2; ++t) {
    unsigned ptile = pbase + (unsigned)t * 128u;
    int j0w = (int)(ptile & 511);

    // consume raw regs into bf16 fragments (frees raw for the next tile)
    bf16x8 efrag[2][2];
    float adjv[2];
#pragma unroll
    for (int np = 0; np < 2; ++np) {
#pragma unroll
      for (int s = 0; s < 2; ++s) {
        float tmp[8];
        *(float4*)tmp = raw[np][s * 2];
        *(float4*)(tmp + 4) = raw[np][s * 2 + 1];
        efrag[np][s] = pack8(tmp);
      }
      adjv[np] = adjraw[np];
    }

    // issue NEXT tile's loads now — latency hides under this tile's compute
    if (t == 0) {
      unsigned pnext = pbase + 128u;
#pragma unroll
      for (int np = 0; np < 2; ++np) {
        const float* er = edge + (size_t)(pnext + np * 16 + lr) * 64 + lg * 8;
        raw[np][0] = *(const float4*)er;
        raw[np][1] = *(const float4*)(er + 4);
        raw[np][2] = *(const float4*)(er + 32);
        raw[np][3] = *(const float4*)(er + 36);
        adjraw[np] = adj[pnext + np * 16 + lr];
      }
    }

    const float* u1b = u1 + ((size_t)(b * N_ + j0w)) * G_;

    f32x4 yo[2][4];

    // prefetch s=0 weight fragments for mg=0 (latency overlaps u1 prefetch below)
    bf16x8 wf0[6];
#pragma unroll
    for (int w = 0; w < 6; ++w) {
      int R = (0 + 4 * w) * 16 + lr;
      wf0[w] = *(const bf16x8*)(Bc + R * 128 +
                                ((0 * 64 + lg * 16) ^ ((R & 7) << 4)));
    }

#pragma unroll
    for (int mg = 0; mg < 4; ++mg) {   // feature block: e = mg*16 + lg*4 + reg
      int e0 = mg * 16 + lg * 4;

      // u1 prefetch for BOTH np, issued before the MFMA cluster so the L2
      // latency hides under the ds_reads + 24 MFMAs below
      f32x4 u1v[2][3];
#pragma unroll
      for (int np = 0; np < 2; ++np) {
        const float* u1r = u1b + (size_t)(np * 16 + lr) * G_;
        u1v[np][0] = *(const f32x4*)(u1r + e0);
        u1v[np][1] = *(const f32x4*)(u1r + 64 + e0);
        u1v[np][2] = *(const f32x4*)(u1r + 128 + e0);
      }

      f32x4 acc[2][6];
      f32x4 zero = {0.f, 0.f, 0.f, 0.f};
#pragma unroll
      for (int np = 0; np < 2; ++np)
#pragma unroll
        for (int w = 0; w < 6; ++w) acc[np][w] = zero;

      // s=1 fragments for this mg (s=0 already in wf0 from prefetch)
      bf16x8 wf1[6];
#pragma unroll
      for (int w = 0; w < 6; ++w) {
        int R = (mg + 4 * w) * 16 + lr;
        wf1[w] = *(const bf16x8*)(Bc + R * 128 +
                                  ((64 + lg * 16) ^ ((R & 7) << 4)));
      }

      // MFMA cluster: s=0 from prefetched wf0, s=1 from wf1
#pragma unroll
      for (int np = 0; np < 2; ++np)
#pragma unroll
        for (int w = 0; w < 6; ++w)
          acc[np][w] = __builtin_amdgcn_mfma_f32_16x16x32_bf16(
              wf0[w], efrag[np][0], acc[np][w], 0, 0, 0);
#pragma unroll
      for (int np = 0; np < 2; ++np)
#pragma unroll
        for (int w = 0; w < 6; ++w)
          acc[np][w] = __builtin_amdgcn_mfma_f32_16x16x32_bf16(
              wf1[w], efrag[np][1], acc[np][w], 0, 0, 0);

      // prefetch NEXT mg's s=0 fragments BEFORE the epilogue — their ds_read
      // issue+latency hides under the ~400cy TRANS gate chain below
      if (mg < 3) {
#pragma unroll
        for (int w = 0; w < 6; ++w) {
          int R = (mg + 1 + 4 * w) * 16 + lr;
          wf0[w] = *(const bf16x8*)(Bc + R * 128 +
                                    ((0 * 64 + lg * 16) ^ ((R & 7) << 4)));
        }
      }

      // per-mg broadcast constants (L1/L2-hot, tiny)
      f32x4 u2v0 = *(const f32x4*)(u2r + e0);
      f32x4 u2v1 = *(const f32x4*)(u2r + 64 + e0);
      f32x4 u2v2 = *(const f32x4*)(u2r + 128 + e0);
      f32x4 bc0 = *(const f32x4*)(bih + e0) + *(const f32x4*)(bhh + e0);
      f32x4 bc1 = *(const f32x4*)(bih + 64 + e0) + *(const f32x4*)(bhh + 64 + e0);
      f32x4 bi2 = *(const f32x4*)(bih + 128 + e0);
      f32x4 bh2 = *(const f32x4*)(bhh + 128 + e0);

#pragma unroll
      for (int np = 0; np < 2; ++np) {
        // residual edge values from efrag via LDS crossbar (no global re-read)
        union { bf16x8 v; int d[4]; } ef;
        ef.v = efrag[np][mg >> 1];
        int addr = (mg & 1) ? addrO : addrE;
        int r0 = __builtin_amdgcn_ds_bpermute(addr, ef.d[0]);
        int r1 = __builtin_amdgcn_ds_bpermute(addr, ef.d[1]);
        int r2 = __builtin_amdgcn_ds_bpermute(addr, ef.d[2]);
        int r3 = __builtin_amdgcn_ds_bpermute(addr, ef.d[3]);
        bool hi = (lg & 1);
        unsigned w0 = (unsigned)(hi ? r2 : r0);
        unsigned w1 = (unsigned)(hi ? r3 : r1);
        float eva[4];
        eva[0] = __uint_as_float(w0 << 16);
        eva[1] = __uint_as_float(w0 & 0xffff0000u);
        eva[2] = __uint_as_float(w1 << 16);
        eva[3] = __uint_as_float(w1 & 0xffff0000u);

        float a = adjv[np];
        f32x4 yv;
#pragma unroll
        for (int reg = 0; reg < 4; ++reg) {
          float s1 = a * (acc[np][0][reg] + u1v[np][0][reg] + u2v0[reg]) +
                     bc0[reg] + acc[np][3][reg];
          float s2 = a * (acc[np][1][reg] + u1v[np][1][reg] + u2v1[reg]) +
                     bc1[reg] + acc[np][4][reg];
          float gin = a * (acc[np][2][reg] + u1v[np][2][reg] + u2v2[reg]) +
                      bi2[reg];
          float ghn = acc[np][5][reg] + bh2[reg];
          float r = sigm(s1);
          float z = sigm(s2);
          float tt = gin + r * ghn;
          float n = 2.f * sigm(2.f * tt) - 1.f;      // tanh(tt)
          float y = n + z * (eva[reg] - n);
          yv[reg] = y * sigm(y);                     // silu
        }
        yo[np][mg] = yv;
      }
    }

    // tight full-row stores: each 256B out row written in 4 back-to-back float4s
#pragma unroll
    for (int np = 0; np < 2; ++np) {
      size_t P = ptile + np * 16 + lr;
      float* op = out + P * 64 + lg * 4;
#pragma unroll
      for (int mg = 0; mg < 4; ++mg)
        *(f32x4*)(op + mg * 16) = yo[np][mg];
    }
  }
}

// ================= fallback fp32 path (used only if ws too small) =================
__global__ __launch_bounds__(64) void mkernelF(const float* __restrict__ edge,
                                               const float* __restrict__ adj,
                                               const float* __restrict__ Wlin,
                                               const float* __restrict__ blin,
                                               const float* __restrict__ h,
                                               float* __restrict__ mout) {
  size_t p = (size_t)blockIdx.x * 64 + threadIdx.x;
  int b = (int)(p >> 18), i = (int)((p >> 9) & 511), j = (int)(p & 511);
  float ed[E_], hj[E_], hi[E_];
  const float4* ep = (const float4*)(edge + p * E_);
  const float4* hjp = (const float4*)(h + ((size_t)(b * N_ + j)) * E_);
  const float4* hip = (const float4*)(h + ((size_t)(b * N_ + i)) * E_);
#pragma unroll
  for (int k = 0; k < E_ / 4; ++k) {
    float4 v = ep[k];
    ed[4 * k] = v.x; ed[4 * k + 1] = v.y; ed[4 * k + 2] = v.z; ed[4 * k + 3] = v.w;
    float4 a = hjp[k];
    hj[4 * k] = a.x; hj[4 * k + 1] = a.y; hj[4 * k + 2] = a.z; hj[4 * k + 3] = a.w;
    float4 u = hip[k];
    hi[4 * k] = u.x; hi[4 * k + 1] = u.y; hi[4 * k + 2] = u.z; hi[4 * k + 3] = u.w;
  }
  float av = adj[p];
  float* mo = mout + p * E_;
  for (int e = 0; e < E_; ++e) {
    const float* w = Wlin + e * LIN_IN_;
    float acc = blin[e];
#pragma unroll
    for (int k = 0; k < E_; ++k)
      acc += hj[k] * w[k] + ed[k] * w[64 + k] + hi[k] * w[128 + k];
    mo[e] = av * acc;
  }
}
__global__ __launch_bounds__(64) void gkernelF(const float* __restrict__ edge,
                                               const float* mbuf,
                                               const float* __restrict__ wih,
                                               const float* __restrict__ whh,
                                               const float* __restrict__ bih,
                                               const float* __restrict__ bhh,
                                               float* out) {
  size_t p = (size_t)blockIdx.x * 64 + threadIdx.x;
  float ed[E_], m[E_];
  const float4* ep = (const float4*)(edge + p * E_);
  const float4* mp = (const float4*)(mbuf + p * E_);
#pragma unroll
  for (int k = 0; k < E_ / 4; ++k) {
    float4 v = ep[k];
    ed[4 * k] = v.x; ed[4 * k + 1] = v.y; ed[4 * k + 2] = v.z; ed[4 * k + 3] = v.w;
    float4 u = mp[k];
    m[4 * k] = u.x; m[4 * k + 1] = u.y; m[4 * k + 2] = u.z; m[4 * k + 3] = u.w;
  }
  float* op = out + p * E_;
  for (int e = 0; e < E_; ++e) {
    const float* wr = wih + e * 64;
    const float* wz = wih + (64 + e) * 64;
    const float* wn = wih + (128 + e) * 64;
    const float* vr = whh + e * 64;
    const float* vz = whh + (64 + e) * 64;
    const float* vn = whh + (128 + e) * 64;
    float ir = bih[e], iz = bih[64 + e], inn = bih[128 + e];
    float hr = bhh[e], hz = bhh[64 + e], hn = bhh[128 + e];
#pragma unroll
    for (int k = 0; k < E_; ++k) {
      float mk = m[k], ek = ed[k];
      ir += mk * wr[k]; iz += mk * wz[k]; inn += mk * wn[k];
      hr += ek * vr[k]; hz += ek * vz[k]; hn += ek * vn[k];
    }
    float r = sigm(ir + hr);
    float z = sigm(iz + hz);
    float nv = tanh_f(inn + r * hn);
    float nh = (1.f - z) * nv + z * ed[e];
    op[e] = nh * sigm(nh);
  }
}

extern "C" void kernel_launch(void* const* d_in, const int* in_sizes, int n_in,
                              void* d_out, int out_size, void* d_ws, size_t ws_size,
                              hipStream_t stream) {
  const float* h    = (const float*)d_in[0];
  const float* edge = (const float*)d_in[1];
  const float* adj  = (const float*)d_in[2];
  const float* Wlin = (const float*)d_in[3];
  const float* blin = (const float*)d_in[4];
  const float* wih  = (const float*)d_in[5];
  const float* whh  = (const float*)d_in[6];
  const float* bih  = (const float*)d_in[7];
  const float* bhh  = (const float*)d_in[8];
  float* out = (float*)d_out;

  // ws layout (bytes): Bt bf16 49152 | V1 49152 | V2 49152 | ub 1024 | u1 786432 | u2p 786432
  const size_t OFF_V1 = 49152, OFF_V2 = 98304, OFF_UB = 147456,
               OFF_U1 = 148480, OFF_U2 = 148480 + 786432;
  const size_t WS_NEEDED = OFF_U2 + 786432;
  if (ws_size >= WS_NEEDED) {
    char* w = (char*)d_ws;
    unsigned short* Bt = (unsigned short*)w;
    float* V1 = (float*)(w + OFF_V1);
    float* V2 = (float*)(w + OFF_V2);
    float* ub = (float*)(w + OFF_UB);
    float* u1 = (float*)(w + OFF_U1);
    float* u2p = (float*)(w + OFF_U2);
    prep1<<<384, 64, 0, stream>>>(Wlin, blin, wih, whh, Bt, V1, V2, ub);
    prep2<<<B_ * N_, 192, 0, stream>>>(h, V1, V2, ub, u1, u2p);
    // 2048 blocks x 4 waves x 32 pairs x 2 tiles = 524288 pairs
    fusedT19<<<2048, 256, 0, stream>>>(edge, adj, Bt, u1, u2p, bih, bhh, out);
  } else {
    size_t npairs = (size_t)B_ * N_ * N_;
    int blocks = (int)(npairs / 64);
    mkernelF<<<blocks, 64, 0, stream>>>(edge, adj, Wlin, blin, h, out);
    gkernelF<<<blocks, 64, 0, stream>>>(edge, out, wih, whh, bih, bhh, out);
  }
}

// Round 24
// 123.298 us; speedup vs baseline: 1.2433x; 1.2433x over previous
//
#include <hip/hip_runtime.h>
#include <hip/hip_bf16.h>

#define B_ 2
#define N_ 512
#define E_ 64
#define G_ 192
#define LIN_IN_ 192

typedef __attribute__((ext_vector_type(8))) short bf16x8;
typedef __attribute__((ext_vector_type(4))) float f32x4;

__device__ __forceinline__ unsigned short f2bf(float x) {
  unsigned u = __float_as_uint(x);
  unsigned r = (u + 0x7FFFu + ((u >> 16) & 1u)) >> 16;
  return (unsigned short)r;
}
// fast sigmoid: v_rcp_f32 (1 ULP) instead of IEEE divide (R12-verified correct)
__device__ __forceinline__ float sigm(float x) {
  return __builtin_amdgcn_rcpf(1.f + __expf(-x));
}
__device__ __forceinline__ float tanh_f(float x) {
  float e = __expf(-2.f * fabsf(x));
  return copysignf((1.f - e) * __builtin_amdgcn_rcpf(1.f + e), x);
}
__device__ __forceinline__ bf16x8 pack8(const float* t) {
  union { bf16x8 v; __hip_bfloat16 h[8]; } u;
#pragma unroll
  for (int k = 0; k < 8; ++k) u.h[k] = __float2bfloat16(t[k]);
  return u.v;
}

// ---------- prep1: Bt[384][64] bf16 = [W2e (wih·We) ; whh]; V1 = wih·W1,
//            V2 = wih·W2h (fp32); ub = wih·b_lin ----------
__global__ __launch_bounds__(64) void prep1(const float* __restrict__ Wlin,
                                            const float* __restrict__ blin,
                                            const float* __restrict__ wih,
                                            const float* __restrict__ whh,
                                            unsigned short* __restrict__ Bt,
                                            float* __restrict__ V1,
                                            float* __restrict__ V2,
                                            float* __restrict__ ub) {
  int g = blockIdx.x;   // 0..383
  int f = threadIdx.x;  // 0..63
  if (g < G_) {
    const float* wr = wih + g * 64;  // uniform -> s_load
    float aw = 0.f, a1 = 0.f, a2 = 0.f;
#pragma unroll
    for (int e = 0; e < 64; ++e) {
      float wv = wr[e];
      a1 += wv * Wlin[e * LIN_IN_ + f];          // V1 = wih·W1
      aw += wv * Wlin[e * LIN_IN_ + 64 + f];     // W2e = wih·We
      a2 += wv * Wlin[e * LIN_IN_ + 128 + f];    // V2 = wih·W2h
    }
    Bt[g * 64 + f] = f2bf(aw);
    V1[g * 64 + f] = a1;
    V2[g * 64 + f] = a2;
    if (f == 0) {
      float s = 0.f;
      for (int e = 0; e < 64; ++e) s += wr[e] * blin[e];
      ub[g] = s;
    }
  } else {
    int gh = g - G_;
    Bt[g * 64 + f] = f2bf(whh[gh * 64 + f]);
  }
}

// ---------- prep2: u1[row,g] = V1[g,:]·h[row,:]; u2p[row,g] = V2[g,:]·h[row,:] + ub[g] ----------
__global__ __launch_bounds__(192) void prep2(const float* __restrict__ h,
                                             const float* __restrict__ V1,
                                             const float* __restrict__ V2,
                                             const float* __restrict__ ub,
                                             float* __restrict__ u1,
                                             float* __restrict__ u2p) {
  int row = blockIdx.x;   // b*N+n
  int g = threadIdx.x;    // 0..191
  const float* hr = h + (size_t)row * 64;  // uniform
  float a1 = 0.f, a2 = 0.f;
#pragma unroll
  for (int f = 0; f < 64; ++f) {
    float hv = hr[f];
    a1 += V1[g * 64 + f] * hv;
    a2 += V2[g * 64 + f] * hv;
  }
  u1[(size_t)row * G_ + g] = a1;
  u2p[(size_t)row * G_ + g] = a2 + ub[g];
}

// ---------- fusedT14 (FINAL CHAMPION, 124.2 us, VGPR=128): depth-2 edge
// pipeline, tile-0 loads issued before weight staging (overlap staging+
// barrier), same (b,i)-row tiles (u2 hoisted), per-mg u1 prefetch,
// rcp-sigmoids, bpermute residual recovery, register-buffered full-row
// stores. Established plateau: 11 orthogonal optimization attempts
// (occupancy x4, VALU diet, prefetch/hoist variants x4, persistent blocks,
// deeper pipelines, setprio) all neutral-or-negative; only the depth-2
// static pipeline (R13, +23us) moved the needle. Any buffer spanning an
// mg/t loop iteration balloons VGPR 128->220+ (R10/R14/R18/R23). ----------
__global__ __launch_bounds__(256) void fusedT14(const float* __restrict__ edge,
                                                const float* __restrict__ adj,
                                                const unsigned short* __restrict__ BtW,
                                                const float* __restrict__ u1,
                                                const float* __restrict__ u2p,
                                                const float* __restrict__ bih,
                                                const float* __restrict__ bhh,
                                                float* __restrict__ out) {
  __shared__ uint4 Bs4[3072];  // 48 KB: 384 rows x 128B, XOR-swizzled (0-conflict verified)
  char* Bc = (char*)Bs4;
  int tid = threadIdx.x;

  int lane = tid & 63, wave = tid >> 6;
  unsigned pbase = blockIdx.x * 256u + wave * 32u;
  int b = pbase >> 18;
  int iN = (pbase >> 9) & 511;
  int lr = lane & 15, lg = lane >> 4;

  // ---- issue tile-0 edge/adj loads FIRST: latency overlaps staging+barrier ----
  float4 raw[2][4];
  float adjraw[2];
#pragma unroll
  for (int np = 0; np < 2; ++np) {
    const float* er = edge + (size_t)(pbase + np * 16 + lr) * 64 + lg * 8;
    raw[np][0] = *(const float4*)er;
    raw[np][1] = *(const float4*)(er + 4);
    raw[np][2] = *(const float4*)(er + 32);
    raw[np][3] = *(const float4*)(er + 36);
    adjraw[np] = adj[pbase + np * 16 + lr];
  }

  // ---- weight staging (overlapped with the edge loads above) ----
  const uint4* src = (const uint4*)BtW;
#pragma unroll
  for (int it = 0; it < 12; ++it) {
    int c = tid + it * 256;          // 3072 chunks of 16B
    int row = c >> 3;
    *(uint4*)(Bc + row * 128 + (((c & 7) * 16) ^ ((row & 7) << 4))) = src[c];
  }
  __syncthreads();

  // bpermute source-lane addresses (byte addr = srclane*4)
  int addrE = (lr + 16 * (lg >> 1)) << 2;   // mg even
  int addrO = addrE + 128;                  // mg odd

  // u2 row is shared by both tiles (same b, iN) — hoisted
  const float* u2r = u2p + ((size_t)(b * N_ + iN)) * G_;

#pragma unroll
  for (int t = 0; t < 2; ++t) {
    unsigned ptile = pbase + (unsigned)t * 128u;
    int j0w = (int)(ptile & 511);

    // consume raw regs into bf16 fragments (frees raw for the next tile)
    bf16x8 efrag[2][2];
    float adjv[2];
#pragma unroll
    for (int np = 0; np < 2; ++np) {
#pragma unroll
      for (int s = 0; s < 2; ++s) {
        float tmp[8];
        *(float4*)tmp = raw[np][s * 2];
        *(float4*)(tmp + 4) = raw[np][s * 2 + 1];
        efrag[np][s] = pack8(tmp);
      }
      adjv[np] = adjraw[np];
    }

    // issue NEXT tile's loads now — latency hides under this tile's compute
    if (t == 0) {
      unsigned pnext = pbase + 128u;
#pragma unroll
      for (int np = 0; np < 2; ++np) {
        const float* er = edge + (size_t)(pnext + np * 16 + lr) * 64 + lg * 8;
        raw[np][0] = *(const float4*)er;
        raw[np][1] = *(const float4*)(er + 4);
        raw[np][2] = *(const float4*)(er + 32);
        raw[np][3] = *(const float4*)(er + 36);
        adjraw[np] = adj[pnext + np * 16 + lr];
      }
    }

    const float* u1b = u1 + ((size_t)(b * N_ + j0w)) * G_;

    f32x4 yo[2][4];

#pragma unroll
    for (int mg = 0; mg < 4; ++mg) {   // feature block: e = mg*16 + lg*4 + reg
      int e0 = mg * 16 + lg * 4;

      // u1 prefetch for BOTH np, issued before the MFMA cluster so the L2
      // latency hides under the 12 ds_reads + 24 MFMAs below
      f32x4 u1v[2][3];
#pragma unroll
      for (int np = 0; np < 2; ++np) {
        const float* u1r = u1b + (size_t)(np * 16 + lr) * G_;
        u1v[np][0] = *(const f32x4*)(u1r + e0);
        u1v[np][1] = *(const f32x4*)(u1r + 64 + e0);
        u1v[np][2] = *(const f32x4*)(u1r + 128 + e0);
      }

      f32x4 acc[2][6];
      f32x4 zero = {0.f, 0.f, 0.f, 0.f};
#pragma unroll
      for (int np = 0; np < 2; ++np)
#pragma unroll
        for (int w = 0; w < 6; ++w) acc[np][w] = zero;

      const int tiles[6] = {mg, mg + 4, mg + 8, mg + 12, mg + 16, mg + 20};
#pragma unroll
      for (int s = 0; s < 2; ++s) {
        bf16x8 wf[6];
#pragma unroll
        for (int w = 0; w < 6; ++w) {
          int R = tiles[w] * 16 + lr;
          wf[w] = *(const bf16x8*)(Bc + R * 128 +
                                   ((s * 64 + lg * 16) ^ ((R & 7) << 4)));
        }
#pragma unroll
        for (int np = 0; np < 2; ++np)
#pragma unroll
          for (int w = 0; w < 6; ++w)
            acc[np][w] = __builtin_amdgcn_mfma_f32_16x16x32_bf16(
                wf[w], efrag[np][s], acc[np][w], 0, 0, 0);
      }

      // per-mg broadcast constants (L1/L2-hot, tiny)
      f32x4 u2v0 = *(const f32x4*)(u2r + e0);
      f32x4 u2v1 = *(const f32x4*)(u2r + 64 + e0);
      f32x4 u2v2 = *(const f32x4*)(u2r + 128 + e0);
      f32x4 bc0 = *(const f32x4*)(bih + e0) + *(const f32x4*)(bhh + e0);
      f32x4 bc1 = *(const f32x4*)(bih + 64 + e0) + *(const f32x4*)(bhh + 64 + e0);
      f32x4 bi2 = *(const f32x4*)(bih + 128 + e0);
      f32x4 bh2 = *(const f32x4*)(bhh + 128 + e0);

#pragma unroll
      for (int np = 0; np < 2; ++np) {
        // residual edge values from efrag via LDS crossbar (no global re-read)
        union { bf16x8 v; int d[4]; } ef;
        ef.v = efrag[np][mg >> 1];
        int addr = (mg & 1) ? addrO : addrE;
        int r0 = __builtin_amdgcn_ds_bpermute(addr, ef.d[0]);
        int r1 = __builtin_amdgcn_ds_bpermute(addr, ef.d[1]);
        int r2 = __builtin_amdgcn_ds_bpermute(addr, ef.d[2]);
        int r3 = __builtin_amdgcn_ds_bpermute(addr, ef.d[3]);
        bool hi = (lg & 1);
        unsigned w0 = (unsigned)(hi ? r2 : r0);
        unsigned w1 = (unsigned)(hi ? r3 : r1);
        float eva[4];
        eva[0] = __uint_as_float(w0 << 16);
        eva[1] = __uint_as_float(w0 & 0xffff0000u);
        eva[2] = __uint_as_float(w1 << 16);
        eva[3] = __uint_as_float(w1 & 0xffff0000u);

        float a = adjv[np];
        f32x4 yv;
#pragma unroll
        for (int reg = 0; reg < 4; ++reg) {
          float s1 = a * (acc[np][0][reg] + u1v[np][0][reg] + u2v0[reg]) +
                     bc0[reg] + acc[np][3][reg];
          float s2 = a * (acc[np][1][reg] + u1v[np][1][reg] + u2v1[reg]) +
                     bc1[reg] + acc[np][4][reg];
          float gin = a * (acc[np][2][reg] + u1v[np][2][reg] + u2v2[reg]) +
                      bi2[reg];
          float ghn = acc[np][5][reg] + bh2[reg];
          float r = sigm(s1);
          float z = sigm(s2);
          float tt = gin + r * ghn;
          float n = 2.f * sigm(2.f * tt) - 1.f;      // tanh(tt)
          float y = n + z * (eva[reg] - n);
          yv[reg] = y * sigm(y);                     // silu
        }
        yo[np][mg] = yv;
      }
    }

    // tight full-row stores: each 256B out row written in 4 back-to-back float4s
#pragma unroll
    for (int np = 0; np < 2; ++np) {
      size_t P = ptile + np * 16 + lr;
      float* op = out + P * 64 + lg * 4;
#pragma unroll
      for (int mg = 0; mg < 4; ++mg)
        *(f32x4*)(op + mg * 16) = yo[np][mg];
    }
  }
}

// ================= fallback fp32 path (used only if ws too small) =================
__global__ __launch_bounds__(64) void mkernelF(const float* __restrict__ edge,
                                               const float* __restrict__ adj,
                                               const float* __restrict__ Wlin,
                                               const float* __restrict__ blin,
                                               const float* __restrict__ h,
                                               float* __restrict__ mout) {
  size_t p = (size_t)blockIdx.x * 64 + threadIdx.x;
  int b = (int)(p >> 18), i = (int)((p >> 9) & 511), j = (int)(p & 511);
  float ed[E_], hj[E_], hi[E_];
  const float4* ep = (const float4*)(edge + p * E_);
  const float4* hjp = (const float4*)(h + ((size_t)(b * N_ + j)) * E_);
  const float4* hip = (const float4*)(h + ((size_t)(b * N_ + i)) * E_);
#pragma unroll
  for (int k = 0; k < E_ / 4; ++k) {
    float4 v = ep[k];
    ed[4 * k] = v.x; ed[4 * k + 1] = v.y; ed[4 * k + 2] = v.z; ed[4 * k + 3] = v.w;
    float4 a = hjp[k];
    hj[4 * k] = a.x; hj[4 * k + 1] = a.y; hj[4 * k + 2] = a.z; hj[4 * k + 3] = a.w;
    float4 u = hip[k];
    hi[4 * k] = u.x; hi[4 * k + 1] = u.y; hi[4 * k + 2] = u.z; hi[4 * k + 3] = u.w;
  }
  float av = adj[p];
  float* mo = mout + p * E_;
  for (int e = 0; e < E_; ++e) {
    const float* w = Wlin + e * LIN_IN_;
    float acc = blin[e];
#pragma unroll
    for (int k = 0; k < E_; ++k)
      acc += hj[k] * w[k] + ed[k] * w[64 + k] + hi[k] * w[128 + k];
    mo[e] = av * acc;
  }
}
__global__ __launch_bounds__(64) void gkernelF(const float* __restrict__ edge,
                                               const float* mbuf,
                                               const float* __restrict__ wih,
                                               const float* __restrict__ whh,
                                               const float* __restrict__ bih,
                                               const float* __restrict__ bhh,
                                               float* out) {
  size_t p = (size_t)blockIdx.x * 64 + threadIdx.x;
  float ed[E_], m[E_];
  const float4* ep = (const float4*)(edge + p * E_);
  const float4* mp = (const float4*)(mbuf + p * E_);
#pragma unroll
  for (int k = 0; k < E_ / 4; ++k) {
    float4 v = ep[k];
    ed[4 * k] = v.x; ed[4 * k + 1] = v.y; ed[4 * k + 2] = v.z; ed[4 * k + 3] = v.w;
    float4 u = mp[k];
    m[4 * k] = u.x; m[4 * k + 1] = u.y; m[4 * k + 2] = u.z; m[4 * k + 3] = u.w;
  }
  float* op = out + p * E_;
  for (int e = 0; e < E_; ++e) {
    const float* wr = wih + e * 64;
    const float* wz = wih + (64 + e) * 64;
    const float* wn = wih + (128 + e) * 64;
    const float* vr = whh + e * 64;
    const float* vz = whh + (64 + e) * 64;
    const float* vn = whh + (128 + e) * 64;
    float ir = bih[e], iz = bih[64 + e], inn = bih[128 + e];
    float hr = bhh[e], hz = bhh[64 + e], hn = bhh[128 + e];
#pragma unroll
    for (int k = 0; k < E_; ++k) {
      float mk = m[k], ek = ed[k];
      ir += mk * wr[k]; iz += mk * wz[k]; inn += mk * wn[k];
      hr += ek * vr[k]; hz += ek * vz[k]; hn += ek * vn[k];
    }
    float r = sigm(ir + hr);
    float z = sigm(iz + hz);
    float nv = tanh_f(inn + r * hn);
    float nh = (1.f - z) * nv + z * ed[e];
    op[e] = nh * sigm(nh);
  }
}

extern "C" void kernel_launch(void* const* d_in, const int* in_sizes, int n_in,
                              void* d_out, int out_size, void* d_ws, size_t ws_size,
                              hipStream_t stream) {
  const float* h    = (const float*)d_in[0];
  const float* edge = (const float*)d_in[1];
  const float* adj  = (const float*)d_in[2];
  const float* Wlin = (const float*)d_in[3];
  const float* blin = (const float*)d_in[4];
  const float* wih  = (const float*)d_in[5];
  const float* whh  = (const float*)d_in[6];
  const float* bih  = (const float*)d_in[7];
  const float* bhh  = (const float*)d_in[8];
  float* out = (float*)d_out;

  // ws layout (bytes): Bt bf16 49152 | V1 49152 | V2 49152 | ub 1024 | u1 786432 | u2p 786432
  const size_t OFF_V1 = 49152, OFF_V2 = 98304, OFF_UB = 147456,
               OFF_U1 = 148480, OFF_U2 = 148480 + 786432;
  const size_t WS_NEEDED = OFF_U2 + 786432;
  if (ws_size >= WS_NEEDED) {
    char* w = (char*)d_ws;
    unsigned short* Bt = (unsigned short*)w;
    float* V1 = (float*)(w + OFF_V1);
    float* V2 = (float*)(w + OFF_V2);
    float* ub = (float*)(w + OFF_UB);
    float* u1 = (float*)(w + OFF_U1);
    float* u2p = (float*)(w + OFF_U2);
    prep1<<<384, 64, 0, stream>>>(Wlin, blin, wih, whh, Bt, V1, V2, ub);
    prep2<<<B_ * N_, 192, 0, stream>>>(h, V1, V2, ub, u1, u2p);
    // 2048 blocks x 4 waves x 32 pairs x 2 tiles = 524288 pairs
    fusedT14<<<2048, 256, 0, stream>>>(edge, adj, Bt, u1, u2p, bih, bhh, out);
  } else {
    size_t npairs = (size_t)B_ * N_ * N_;
    int blocks = (int)(npairs / 64);
    mkernelF<<<blocks, 64, 0, stream>>>(edge, adj, Wlin, blin, h, out);
    gkernelF<<<blocks, 64, 0, stream>>>(edge, out, wih, whh, bih, bhh, out);
  }
}